// Round 8
// baseline (326.342 us; speedup 1.0000x reference)
//
#include <hip/hip_runtime.h>

// Fused SLAYER 2-layer SNN forward — 3-kernel balanced bitmask pipeline (R8).
// R7 result: l1 100us @ VALUBusy 77% (near its ~8-waves/CU structural limit);
// pack was uncoalesced (200B lane stride). R8: ballot-based pack (coalesced
// reads + wave-transpose via __ballot), mask layout [n][c][yx] so all mask
// I/O is coalesced. Also fixed R7-l1's weight staging (`if(tid<400)` under
// 256 threads left wL1[256..399] unwritten) with a strided loop.
// Recurrence arithmetic identical to the passing R3/R6/R7 kernels.

#define TC 10   // timesteps per chunk (50 = 5 chunks)

// ---------------- kernel A: ballot pack: spikes -> uint2 masks ----------------
// One wave packs 64 consecutive pixels (in flat (n,c,y,x) order).
__global__ __launch_bounds__(256)
void snn_pack(const float* __restrict__ xin, uint2* __restrict__ xmg)
{
    __shared__ unsigned long long bal[4][50];
    const int tid  = threadIdx.x;
    const int lane = tid & 63;
    const int ws   = tid >> 6;
    const size_t wpx = ((size_t)blockIdx.x * 4 + ws) * 64;  // first pixel of wave
    const float* src = xin + wpx * 50;
#pragma unroll 1
    for (int j = 0; j < 50; ++j) {
        float v = src[j * 64 + lane];            // coalesced 256B per wave-instr
        unsigned long long b = __ballot(v != 0.f);
        if (lane == 0) bal[ws][j] = b;           // bit i of word j = flat bit 64j+i
    }
    __syncthreads();
    // pixel p (=lane) owns flat bits [50p, 50p+50) -> words w, w+1
    const int bitpos = lane * 50;
    const int w = bitpos >> 6, s = bitpos & 63;
    unsigned long long m = bal[ws][w] >> s;
    if (s > 14) m |= bal[ws][w + 1] << (64 - s); // s<=14 never needs word w+1
    m &= (1ull << 50) - 1;
    xmg[wpx + lane] = make_uint2((unsigned)m, (unsigned)(m >> 32));
}

// ---------------- kernel B: layer 1 (conv5x5 + psp + spike) ----------------
#define HS1 20            // halo region 20x20 for 16x16 tile
#define HP1 21            // padded LDS plane stride
__global__ __launch_bounds__(256)
void snn_l1(const uint2* __restrict__ xmg, const float* __restrict__ w1,
            uint2* __restrict__ s1g)
{
    __shared__ __align__(16) uint2 xs[4][HS1 * HP1];
    __shared__ __align__(16) float wL1[400];        // [ic][dy][dx][oc]

    const int tid = threadIdx.x;
    const int n = blockIdx.z, Y0 = blockIdx.y * 16, X0 = blockIdx.x * 16;

    for (int i = tid; i < 400; i += 256) {          // strided: covers ALL 400
        int oc = i & 3, r = i >> 2;
        int ic = r / 25, r2 = r - ic * 25;
        int dy = r2 / 5, dx = r2 - dy * 5;
        wL1[i] = w1[((oc * 4 + ic) * 5 + dy) * 5 + dx];
    }
#pragma unroll
    for (int s = 0; s < 2; ++s) {
        int hp = tid + s * 256;
        if (hp < HS1 * HS1) {
            int hy = hp / HS1, hx = hp - hy * HS1;
            int gy = Y0 + hy - 2, gx = X0 + hx - 2;
            bool ok = gy >= 0 && gy < 128 && gx >= 0 && gx < 128;
            int gi = (gy << 7) + gx;
            int li = hy * HP1 + hx;
#pragma unroll
            for (int c = 0; c < 4; ++c) {
                uint2 v = make_uint2(0u, 0u);
                if (ok) v = xmg[(((size_t)(n * 4 + c)) << 14) + gi];
                xs[c][li] = v;
            }
        }
    }
    __syncthreads();

    const int cy = tid >> 4, cx = tid & 15;
    const int base = cy * HP1 + cx;

    float s1a[4] = {}, s2a[4] = {}, s1b[4] = {}, s2b[4] = {};
    unsigned long long om[4] = {};
    const float R1  = 0.36787944117144233f;   // exp(-1/1)
    const float CO1 = 2.7182818284590452f;    // e/1
    const float CRF = -54.365636569180902f;   // -20e

    for (int chk = 0; chk < 5; ++chk) {
        const int t0 = chk * TC;
        float a[TC][4];
#pragma unroll
        for (int u = 0; u < TC; ++u) { a[u][0]=0.f; a[u][1]=0.f; a[u][2]=0.f; a[u][3]=0.f; }
#pragma unroll 1
        for (int ic = 0; ic < 4; ++ic) {
            const uint2*  xp = &xs[ic][base];
            const float4* wp = (const float4*)&wL1[ic * 100];
#pragma unroll 1
            for (int dy = 0; dy < 5; ++dy) {
#pragma unroll
                for (int dx = 0; dx < 5; ++dx) {
                    uint2 mv = xp[dx];
                    unsigned long long mm = ((unsigned long long)mv.y << 32) | mv.x;
                    unsigned win = (unsigned)(mm >> t0);
                    float4 w = wp[dx];
#pragma unroll
                    for (int u = 0; u < TC; ++u) {
                        float f = (float)((win >> u) & 1u);
                        a[u][0] = fmaf(f, w.x, a[u][0]);
                        a[u][1] = fmaf(f, w.y, a[u][1]);
                        a[u][2] = fmaf(f, w.z, a[u][2]);
                        a[u][3] = fmaf(f, w.w, a[u][3]);
                    }
                }
                xp += HP1; wp += 5;
            }
        }
        unsigned cm[4] = {0, 0, 0, 0};
#pragma unroll
        for (int u = 0; u < TC; ++u) {
#pragma unroll
            for (int oc = 0; oc < 4; ++oc) {
                float ao  = CO1 * s2a[oc];
                float ns1 = fmaf(R1, s1a[oc], a[u][oc]);
                s1a[oc] = ns1;
                s2a[oc] = fmaf(R1, s2a[oc], R1 * ns1);
                float mv = fmaf(CRF, s2b[oc], ao);
                unsigned b = (mv >= 20.f) ? 1u : 0u;
                float spf = (float)b;
                float nb1 = fmaf(R1, s1b[oc], spf);
                s1b[oc] = nb1;
                s2b[oc] = fmaf(R1, s2b[oc], R1 * nb1);
                cm[oc] |= b << u;
            }
        }
#pragma unroll
        for (int oc = 0; oc < 4; ++oc)
            om[oc] |= (unsigned long long)cm[oc] << t0;
    }

    const int yx = (Y0 + cy) * 128 + X0 + cx;
#pragma unroll
    for (int oc = 0; oc < 4; ++oc)
        s1g[(((size_t)(n * 4 + oc)) << 14) + yx] =
            make_uint2((unsigned)om[oc], (unsigned)(om[oc] >> 32));
}

// ---------------- kernel C: layer 2 (conv3x3 + psp + spike) + expand ----------------
#define HS2 18
#define HP2 19
__global__ __launch_bounds__(256)
void snn_l2(const uint2* __restrict__ s1g, const float* __restrict__ w2,
            float* __restrict__ out)
{
    __shared__ __align__(16) uint2 ss[4][HS2 * HP2];
    __shared__ __align__(16) float wL2[144];        // [ic][dy][dx][oc]
    __shared__ unsigned long long oml[256 * 4];

    const int tid = threadIdx.x;
    const int n = blockIdx.z, Y0 = blockIdx.y * 16, X0 = blockIdx.x * 16;

    if (tid < 144) {
        int oc = tid & 3, r = tid >> 2;
        int ic = r / 9, r2 = r - ic * 9;
        int dy = r2 / 3, dx = r2 - dy * 3;
        wL2[tid] = w2[((oc * 4 + ic) * 3 + dy) * 3 + dx];
    }
#pragma unroll
    for (int s = 0; s < 2; ++s) {
        int hp = tid + s * 256;
        if (hp < HS2 * HS2) {
            int hy = hp / HS2, hx = hp - hy * HS2;
            int gy = Y0 + hy - 1, gx = X0 + hx - 1;
            bool ok = gy >= 0 && gy < 128 && gx >= 0 && gx < 128;
            int gi = (gy << 7) + gx;
            int li = hy * HP2 + hx;
#pragma unroll
            for (int c = 0; c < 4; ++c) {
                uint2 v = make_uint2(0u, 0u);
                if (ok) v = s1g[(((size_t)(n * 4 + c)) << 14) + gi];
                ss[c][li] = v;
            }
        }
    }
    __syncthreads();

    const int cy = tid >> 4, cx = tid & 15;
    const int base = cy * HP2 + cx;

    float s1c[4] = {}, s2c[4] = {}, s1d[4] = {}, s2d[4] = {};
    unsigned long long om[4] = {};
    const float R2  = 0.60653065971263342f;   // exp(-1/2)
    const float CO2 = 1.3591409142295226f;    // e/2
    const float CRF = -54.365636569180902f;   // -40e/2

    for (int chk = 0; chk < 5; ++chk) {
        const int t0 = chk * TC;
        float a[TC][4];
#pragma unroll
        for (int u = 0; u < TC; ++u) { a[u][0]=0.f; a[u][1]=0.f; a[u][2]=0.f; a[u][3]=0.f; }
#pragma unroll 1
        for (int ic = 0; ic < 4; ++ic) {
            const uint2*  sp = &ss[ic][base];
            const float4* wp = (const float4*)&wL2[ic * 36];
#pragma unroll 1
            for (int dy = 0; dy < 3; ++dy) {
#pragma unroll
                for (int dx = 0; dx < 3; ++dx) {
                    uint2 mv = sp[dx];
                    unsigned long long mm = ((unsigned long long)mv.y << 32) | mv.x;
                    unsigned win = (unsigned)(mm >> t0);
                    float4 w = wp[dx];
#pragma unroll
                    for (int u = 0; u < TC; ++u) {
                        float f = (float)((win >> u) & 1u);
                        a[u][0] = fmaf(f, w.x, a[u][0]);
                        a[u][1] = fmaf(f, w.y, a[u][1]);
                        a[u][2] = fmaf(f, w.z, a[u][2]);
                        a[u][3] = fmaf(f, w.w, a[u][3]);
                    }
                }
                sp += HP2; wp += 3;
            }
        }
        unsigned cm[4] = {0, 0, 0, 0};
#pragma unroll
        for (int u = 0; u < TC; ++u) {
#pragma unroll
            for (int oc = 0; oc < 4; ++oc) {
                float ao  = CO2 * s2c[oc];
                float ns1 = fmaf(R2, s1c[oc], a[u][oc]);
                s1c[oc] = ns1;
                s2c[oc] = fmaf(R2, s2c[oc], R2 * ns1);
                float mv = fmaf(CRF, s2d[oc], ao);
                unsigned b = (mv >= 40.f) ? 1u : 0u;
                float spf = (float)b;
                float nd1 = fmaf(R2, s1d[oc], spf);
                s1d[oc] = nd1;
                s2d[oc] = fmaf(R2, s2d[oc], R2 * nd1);
                cm[oc] |= b << u;
            }
        }
#pragma unroll
        for (int oc = 0; oc < 4; ++oc)
            om[oc] |= (unsigned long long)cm[oc] << t0;
    }

    // coalesced output expansion via LDS transpose
#pragma unroll
    for (int oc = 0; oc < 4; ++oc) oml[tid * 4 + oc] = om[oc];
    __syncthreads();

    for (int i = tid; i < 256 * 4 * 25; i += 256) {
        int pc = i / 25;
        int j  = i - pc * 25;
        int p  = pc >> 2, c = pc & 3;
        unsigned long long m = oml[p * 4 + c];
        int py = p >> 4, px = p & 15;
        int k = 2 * j;
        float2 v;
        v.x = (float)((unsigned)(m >> k) & 1u);
        v.y = (float)((unsigned)(m >> (k + 1)) & 1u);
        float* o = out + ((size_t)(((n * 4 + c) << 14) + (Y0 + py) * 128 + X0 + px)) * 50;
        *(float2*)(o + k) = v;
    }
}

// ---------------- fallback (ws too small): R6 single fused kernel ----------------
#define TW   16
#define TH   8
#define R1S  (TW + 6)
#define R1R  (TH + 6)
#define R1N  (R1S * R1R)
#define R2S  (TW + 2)
#define R2R  (TH + 2)
#define R2N  (R2S * R2R)

__global__ __launch_bounds__(256)
void snn_fused_fb(const float* __restrict__ xin,
                  const float* __restrict__ w1,
                  const float* __restrict__ w2,
                  float* __restrict__ out)
{
    __shared__ __align__(16) uint2    xm[4][R1N];
    __shared__ unsigned               s1m[4][R2N];
    __shared__ __align__(16) float    wL1[400];
    __shared__ __align__(16) float    wL2[144];

    const int tid = threadIdx.x;
    const int n   = blockIdx.z;
    const int Y0  = blockIdx.y * TH;
    const int X0  = blockIdx.x * TW;

    for (int i = tid; i < 400; i += 256) {
        int oc = i & 3, r = i >> 2;
        int ic = r / 25, r2 = r - ic * 25;
        int dy = r2 / 5, dx = r2 - dy * 5;
        wL1[i] = w1[((oc * 4 + ic) * 5 + dy) * 5 + dx];
    }
    if (tid < 144) {
        int oc = tid & 3, r = tid >> 2;
        int ic = r / 9, r2 = r - ic * 9;
        int dy = r2 / 3, dx = r2 - dy * 3;
        wL2[tid] = w2[((oc * 4 + ic) * 3 + dy) * 3 + dx];
    }
#pragma unroll
    for (int s = 0; s < 2; ++s) {
        int hp = tid + s * 256;
        if (hp < R1N) {
            int hy = hp / R1S, hx = hp - hy * R1S;
            int gy = Y0 + hy - 3, gx = X0 + hx - 3;
            bool inimg = gy >= 0 && gy < 128 && gx >= 0 && gx < 128;
#pragma unroll
            for (int c = 0; c < 4; ++c) {
                unsigned m0 = 0, m1 = 0;
                if (inimg) {
                    const float2* p = (const float2*)
                        (xin + ((size_t)(((n * 4 + c) * 128 + gy) * 128 + gx)) * 50);
#pragma unroll
                    for (int j = 0; j < 25; ++j) {
                        float2 v = p[j];
                        unsigned b0 = (v.x != 0.f) ? 1u : 0u;
                        unsigned b1 = (v.y != 0.f) ? 1u : 0u;
                        int k = 2 * j;
                        if (k < 32) m0 |= (b0 << k) | (b1 << (k + 1));
                        else        m1 |= (b0 << (k - 32)) | (b1 << (k - 31));
                    }
                }
                xm[c][hp] = make_uint2(m0, m1);
            }
        }
    }
    const bool cw = (tid < R2N);
    const int cy = tid / R2S;
    const int cx = tid - cy * R2S;
    const bool cin = cw && (Y0 + cy - 1) >= 0 && (Y0 + cy - 1) < 128
                        && (X0 + cx - 1) >= 0 && (X0 + cx - 1) < 128;
    const int xbase = cy * R1S + cx;
    const bool iw = (tid < TW * TH);
    const int iy = tid >> 4, ix = tid & 15;
    const int ibase = iy * R2S + ix;

    float s1a[4] = {}, s2a[4] = {}, s1b[4] = {}, s2b[4] = {};
    float s1c[4] = {}, s2c[4] = {}, s1d[4] = {}, s2d[4] = {};
    unsigned long long om[4] = {};

    const float R1  = 0.36787944117144233f;
    const float CO1 = 2.7182818284590452f;
    const float R2  = 0.60653065971263342f;
    const float CO2 = 1.3591409142295226f;
    const float CRF = -54.365636569180902f;

    __syncthreads();

    for (int chk = 0; chk < 5; ++chk) {
        const int t0 = chk * TC;
        if (cw) {
            float a[TC][4];
#pragma unroll
            for (int u = 0; u < TC; ++u) { a[u][0]=0.f; a[u][1]=0.f; a[u][2]=0.f; a[u][3]=0.f; }
            if (cin) {
#pragma unroll 1
                for (int ic = 0; ic < 4; ++ic) {
                    const uint2*  xp = &xm[ic][xbase];
                    const float4* wp = (const float4*)&wL1[ic * 100];
#pragma unroll 1
                    for (int dy = 0; dy < 5; ++dy) {
#pragma unroll
                        for (int dx = 0; dx < 5; ++dx) {
                            uint2 m = xp[dx];
                            unsigned long long mm =
                                ((unsigned long long)m.y << 32) | m.x;
                            unsigned win = (unsigned)(mm >> t0);
                            float4 w = wp[dx];
#pragma unroll
                            for (int u = 0; u < TC; ++u) {
                                float f = (float)((win >> u) & 1u);
                                a[u][0] = fmaf(f, w.x, a[u][0]);
                                a[u][1] = fmaf(f, w.y, a[u][1]);
                                a[u][2] = fmaf(f, w.z, a[u][2]);
                                a[u][3] = fmaf(f, w.w, a[u][3]);
                            }
                        }
                        xp += R1S; wp += 5;
                    }
                }
            }
            unsigned cm[4] = {0, 0, 0, 0};
#pragma unroll
            for (int u = 0; u < TC; ++u) {
#pragma unroll
                for (int oc = 0; oc < 4; ++oc) {
                    float ao  = CO1 * s2a[oc];
                    float ns1 = fmaf(R1, s1a[oc], a[u][oc]);
                    s1a[oc] = ns1;
                    s2a[oc] = fmaf(R1, s2a[oc], R1 * ns1);
                    float mv = fmaf(CRF, s2b[oc], ao);
                    unsigned b = (mv >= 20.f) ? 1u : 0u;
                    float spf = (float)b;
                    float nb1 = fmaf(R1, s1b[oc], spf);
                    s1b[oc] = nb1;
                    s2b[oc] = fmaf(R1, s2b[oc], R1 * nb1);
                    cm[oc] |= b << u;
                }
            }
            s1m[0][tid] = cm[0];
            s1m[1][tid] = cm[1];
            s1m[2][tid] = cm[2];
            s1m[3][tid] = cm[3];
        }
        __syncthreads();
        if (iw) {
            float a[TC][4];
#pragma unroll
            for (int u = 0; u < TC; ++u) { a[u][0]=0.f; a[u][1]=0.f; a[u][2]=0.f; a[u][3]=0.f; }
#pragma unroll 1
            for (int ic = 0; ic < 4; ++ic) {
                const unsigned* sp = &s1m[ic][ibase];
                const float4*   wp = (const float4*)&wL2[ic * 36];
#pragma unroll 1
                for (int dy = 0; dy < 3; ++dy) {
#pragma unroll
                    for (int dx = 0; dx < 3; ++dx) {
                        unsigned win = sp[dx];
                        float4 w = wp[dx];
#pragma unroll
                        for (int u = 0; u < TC; ++u) {
                            float f = (float)((win >> u) & 1u);
                            a[u][0] = fmaf(f, w.x, a[u][0]);
                            a[u][1] = fmaf(f, w.y, a[u][1]);
                            a[u][2] = fmaf(f, w.z, a[u][2]);
                            a[u][3] = fmaf(f, w.w, a[u][3]);
                        }
                    }
                    sp += R2S; wp += 3;
                }
            }
            unsigned cm[4] = {0, 0, 0, 0};
#pragma unroll
            for (int u = 0; u < TC; ++u) {
#pragma unroll
                for (int oc = 0; oc < 4; ++oc) {
                    float ao  = CO2 * s2c[oc];
                    float ns1 = fmaf(R2, s1c[oc], a[u][oc]);
                    s1c[oc] = ns1;
                    s2c[oc] = fmaf(R2, s2c[oc], R2 * ns1);
                    float mv = fmaf(CRF, s2d[oc], ao);
                    unsigned b = (mv >= 40.f) ? 1u : 0u;
                    float spf = (float)b;
                    float nd1 = fmaf(R2, s1d[oc], spf);
                    s1d[oc] = nd1;
                    s2d[oc] = fmaf(R2, s2d[oc], R2 * nd1);
                    cm[oc] |= b << u;
                }
            }
#pragma unroll
            for (int oc = 0; oc < 4; ++oc)
                om[oc] |= (unsigned long long)cm[oc] << t0;
        }
        __syncthreads();
    }
    if (iw) {
#pragma unroll
        for (int c = 0; c < 4; ++c) {
            float* p = out + ((size_t)(((n * 4 + c) * 128 + (Y0 + iy)) * 128 + (X0 + ix))) * 50;
            unsigned long long m = om[c];
#pragma unroll
            for (int j = 0; j < 25; ++j) {
                int k = 2 * j;
                float2 v;
                v.x = (float)((unsigned)(m >> k) & 1u);
                v.y = (float)((unsigned)(m >> (k + 1)) & 1u);
                *(float2*)(p + k) = v;
            }
        }
    }
}

extern "C" void kernel_launch(void* const* d_in, const int* in_sizes, int n_in,
                              void* d_out, int out_size, void* d_ws, size_t ws_size,
                              hipStream_t stream) {
    (void)in_sizes; (void)n_in; (void)out_size;
    const float* x  = (const float*)d_in[0];
    const float* w1 = (const float*)d_in[1];
    const float* w2 = (const float*)d_in[2];
    float* o = (float*)d_out;

    if (ws_size >= 2u * 4194304u) {
        uint2* xmg = (uint2*)d_ws;            // 524288 uint2 = 4 MB, [n][c][yx]
        uint2* s1g = xmg + 524288;            // 4 MB, [n][c][yx]
        hipLaunchKernelGGL(snn_pack, dim3(2048), dim3(256), 0, stream, x, xmg);
        hipLaunchKernelGGL(snn_l1, dim3(8, 8, 8), dim3(256), 0, stream, xmg, w1, s1g);
        hipLaunchKernelGGL(snn_l2, dim3(8, 8, 8), dim3(256), 0, stream, s1g, w2, o);
    } else {
        dim3 grid(128 / TW, 128 / TH, 8);
        hipLaunchKernelGGL(snn_fused_fb, grid, dim3(256), 0, stream, x, w1, w2, o);
    }
}

// Round 9
// 324.777 us; speedup vs baseline: 1.0048x; 1.0048x over previous
//
#include <hip/hip_runtime.h>

// SLAYER 2-layer SNN forward — 3-kernel bitmask pipeline (R9).
// R8 analysis: l1 = 103us @ VALUBusy 75%, Occupancy 17% (512 blocks = 2
// waves/SIMD — latency-hiding-starved). R9: split each pixel across 2
// threads (2 input channels each; one shfl_xor exchange; each thread then
// runs 2 of the 4 independent oc recurrences). Wave count x2 (4 waves/SIMD),
// per-wave work /2. Same for l2. All 256 threads per block fully active.
// psp commutes with the per-timestep conv -> conv binary spike masks, psp
// after. Recurrence arithmetic identical to passing R3..R8 kernels.

#define TC 10   // timesteps per chunk (50 = 5 chunks)

// ---------------- kernel A: ballot pack: spikes -> uint2 masks ----------------
__global__ __launch_bounds__(256)
void snn_pack(const float* __restrict__ xin, uint2* __restrict__ xmg)
{
    __shared__ unsigned long long bal[4][50];
    const int tid  = threadIdx.x;
    const int lane = tid & 63;
    const int ws   = tid >> 6;
    const size_t wpx = ((size_t)blockIdx.x * 4 + ws) * 64;
    const float* src = xin + wpx * 50;
#pragma unroll 1
    for (int j = 0; j < 50; ++j) {
        float v = src[j * 64 + lane];            // coalesced 256B / wave-instr
        unsigned long long b = __ballot(v != 0.f);
        if (lane == 0) bal[ws][j] = b;
    }
    __syncthreads();
    const int bitpos = lane * 50;
    const int w = bitpos >> 6, s = bitpos & 63;
    unsigned long long m = bal[ws][w] >> s;
    if (s > 14) m |= bal[ws][w + 1] << (64 - s);
    m &= (1ull << 50) - 1;
    xmg[wpx + lane] = make_uint2((unsigned)m, (unsigned)(m >> 32));
}

// ---------------- kernel B: layer 1 (conv5x5 + psp + spike) ----------------
// 16x8 tile, 2 threads/pixel (h = tid&1 handles ic {2h,2h+1}, then oc {2h,2h+1})
#define HW1 20            // halo width  (16+4)
#define HH1 12            // halo height (8+4)
#define HP1 21            // padded LDS row stride
__global__ __launch_bounds__(256)
void snn_l1(const uint2* __restrict__ xmg, const float* __restrict__ w1,
            uint2* __restrict__ s1g)
{
    __shared__ __align__(16) uint2 xs[4][HH1 * HP1];
    __shared__ __align__(16) float wL1[400];        // [ic][dy][dx][oc]

    const int tid = threadIdx.x;
    const int n = blockIdx.z, Y0 = blockIdx.y * 8, X0 = blockIdx.x * 16;

    for (int i = tid; i < 400; i += 256) {
        int oc = i & 3, r = i >> 2;
        int ic = r / 25, r2 = r - ic * 25;
        int dy = r2 / 5, dx = r2 - dy * 5;
        wL1[i] = w1[((oc * 4 + ic) * 5 + dy) * 5 + dx];
    }
    {
        int hp = tid;
        if (hp < HW1 * HH1) {
            int hy = hp / HW1, hx = hp - hy * HW1;
            int gy = Y0 + hy - 2, gx = X0 + hx - 2;
            bool ok = gy >= 0 && gy < 128 && gx >= 0 && gx < 128;
            int gi = (gy << 7) + gx;
            int li = hy * HP1 + hx;
#pragma unroll
            for (int c = 0; c < 4; ++c) {
                uint2 v = make_uint2(0u, 0u);
                if (ok) v = xmg[(((size_t)(n * 4 + c)) << 14) + gi];
                xs[c][li] = v;
            }
        }
    }
    __syncthreads();

    const int h  = tid & 1;          // half: ic pair / oc pair
    const int px = tid >> 1;         // 0..127
    const int py = px >> 4, pxx = px & 15;
    const int base = py * HP1 + pxx;

    float s1a[2] = {}, s2a[2] = {}, s1b[2] = {}, s2b[2] = {};
    unsigned long long om[2] = {};
    const float R1  = 0.36787944117144233f;   // exp(-1/1)
    const float CO1 = 2.7182818284590452f;    // e/1
    const float CRF = -54.365636569180902f;   // -20e

    for (int chk = 0; chk < 5; ++chk) {
        const int t0 = chk * TC;
        float a[TC][4];
#pragma unroll
        for (int u = 0; u < TC; ++u) { a[u][0]=0.f; a[u][1]=0.f; a[u][2]=0.f; a[u][3]=0.f; }
#pragma unroll 1
        for (int icl = 0; icl < 2; ++icl) {
            const int ic = 2 * h + icl;
            const uint2*  xp = &xs[ic][base];
            const float4* wp = (const float4*)&wL1[ic * 100];
#pragma unroll 1
            for (int dy = 0; dy < 5; ++dy) {
#pragma unroll
                for (int dx = 0; dx < 5; ++dx) {
                    uint2 mv = xp[dx];
                    unsigned long long mm = ((unsigned long long)mv.y << 32) | mv.x;
                    unsigned win = (unsigned)(mm >> t0);
                    float4 w = wp[dx];
#pragma unroll
                    for (int u = 0; u < TC; ++u) {
                        float f = (float)((win >> u) & 1u);
                        a[u][0] = fmaf(f, w.x, a[u][0]);
                        a[u][1] = fmaf(f, w.y, a[u][1]);
                        a[u][2] = fmaf(f, w.z, a[u][2]);
                        a[u][3] = fmaf(f, w.w, a[u][3]);
                    }
                }
                xp += HP1; wp += 5;
            }
        }
        // exchange: each thread keeps full sums for oc {2h, 2h+1}
        unsigned cm0 = 0, cm1 = 0;
#pragma unroll
        for (int u = 0; u < TC; ++u) {
            float give0 = h ? a[u][0] : a[u][2];
            float give1 = h ? a[u][1] : a[u][3];
            float got0 = __shfl_xor(give0, 1);
            float got1 = __shfl_xor(give1, 1);
            float mine0 = h ? a[u][2] : a[u][0];
            float mine1 = h ? a[u][3] : a[u][1];
            float c0 = mine0 + got0;             // conv sum, oc = 2h
            float c1 = mine1 + got1;             // conv sum, oc = 2h+1
            // recurrence (identical arithmetic, 2 ocs per thread)
            float ao0  = CO1 * s2a[0];
            float ns10 = fmaf(R1, s1a[0], c0);
            s1a[0] = ns10;
            s2a[0] = fmaf(R1, s2a[0], R1 * ns10);
            float mv0 = fmaf(CRF, s2b[0], ao0);
            unsigned b0 = (mv0 >= 20.f) ? 1u : 0u;
            float sp0 = (float)b0;
            float nb10 = fmaf(R1, s1b[0], sp0);
            s1b[0] = nb10;
            s2b[0] = fmaf(R1, s2b[0], R1 * nb10);
            cm0 |= b0 << u;

            float ao1  = CO1 * s2a[1];
            float ns11 = fmaf(R1, s1a[1], c1);
            s1a[1] = ns11;
            s2a[1] = fmaf(R1, s2a[1], R1 * ns11);
            float mv1 = fmaf(CRF, s2b[1], ao1);
            unsigned b1 = (mv1 >= 20.f) ? 1u : 0u;
            float sp1 = (float)b1;
            float nb11 = fmaf(R1, s1b[1], sp1);
            s1b[1] = nb11;
            s2b[1] = fmaf(R1, s2b[1], R1 * nb11);
            cm1 |= b1 << u;
        }
        om[0] |= (unsigned long long)cm0 << t0;
        om[1] |= (unsigned long long)cm1 << t0;
    }

    const int yx = (Y0 + py) * 128 + X0 + pxx;
#pragma unroll
    for (int j = 0; j < 2; ++j) {
        int oc = 2 * h + j;
        s1g[(((size_t)(n * 4 + oc)) << 14) + yx] =
            make_uint2((unsigned)om[j], (unsigned)(om[j] >> 32));
    }
}

// ---------------- kernel C: layer 2 (conv3x3 + psp + spike) + expand ----------------
#define HW2 18
#define HH2 10
#define HP2 19
__global__ __launch_bounds__(256)
void snn_l2(const uint2* __restrict__ s1g, const float* __restrict__ w2,
            float* __restrict__ out)
{
    __shared__ __align__(16) uint2 ss[4][HH2 * HP2];
    __shared__ __align__(16) float wL2[144];        // [ic][dy][dx][oc]
    __shared__ unsigned long long oml[128 * 4];

    const int tid = threadIdx.x;
    const int n = blockIdx.z, Y0 = blockIdx.y * 8, X0 = blockIdx.x * 16;

    if (tid < 144) {
        int oc = tid & 3, r = tid >> 2;
        int ic = r / 9, r2 = r - ic * 9;
        int dy = r2 / 3, dx = r2 - dy * 3;
        wL2[tid] = w2[((oc * 4 + ic) * 3 + dy) * 3 + dx];
    }
    {
        int hp = tid;
        if (hp < HW2 * HH2) {
            int hy = hp / HW2, hx = hp - hy * HW2;
            int gy = Y0 + hy - 1, gx = X0 + hx - 1;
            bool ok = gy >= 0 && gy < 128 && gx >= 0 && gx < 128;
            int gi = (gy << 7) + gx;
            int li = hy * HP2 + hx;
#pragma unroll
            for (int c = 0; c < 4; ++c) {
                uint2 v = make_uint2(0u, 0u);
                if (ok) v = s1g[(((size_t)(n * 4 + c)) << 14) + gi];
                ss[c][li] = v;
            }
        }
    }
    __syncthreads();

    const int h  = tid & 1;
    const int px = tid >> 1;
    const int py = px >> 4, pxx = px & 15;
    const int base = py * HP2 + pxx;

    float s1c[2] = {}, s2c[2] = {}, s1d[2] = {}, s2d[2] = {};
    unsigned long long om[2] = {};
    const float R2  = 0.60653065971263342f;   // exp(-1/2)
    const float CO2 = 1.3591409142295226f;    // e/2
    const float CRF = -54.365636569180902f;   // -40e/2

    for (int chk = 0; chk < 5; ++chk) {
        const int t0 = chk * TC;
        float a[TC][4];
#pragma unroll
        for (int u = 0; u < TC; ++u) { a[u][0]=0.f; a[u][1]=0.f; a[u][2]=0.f; a[u][3]=0.f; }
#pragma unroll 1
        for (int icl = 0; icl < 2; ++icl) {
            const int ic = 2 * h + icl;
            const uint2*  sp = &ss[ic][base];
            const float4* wp = (const float4*)&wL2[ic * 36];
#pragma unroll 1
            for (int dy = 0; dy < 3; ++dy) {
#pragma unroll
                for (int dx = 0; dx < 3; ++dx) {
                    uint2 mv = sp[dx];
                    unsigned long long mm = ((unsigned long long)mv.y << 32) | mv.x;
                    unsigned win = (unsigned)(mm >> t0);
                    float4 w = wp[dx];
#pragma unroll
                    for (int u = 0; u < TC; ++u) {
                        float f = (float)((win >> u) & 1u);
                        a[u][0] = fmaf(f, w.x, a[u][0]);
                        a[u][1] = fmaf(f, w.y, a[u][1]);
                        a[u][2] = fmaf(f, w.z, a[u][2]);
                        a[u][3] = fmaf(f, w.w, a[u][3]);
                    }
                }
                sp += HP2; wp += 3;
            }
        }
        unsigned cm0 = 0, cm1 = 0;
#pragma unroll
        for (int u = 0; u < TC; ++u) {
            float give0 = h ? a[u][0] : a[u][2];
            float give1 = h ? a[u][1] : a[u][3];
            float got0 = __shfl_xor(give0, 1);
            float got1 = __shfl_xor(give1, 1);
            float mine0 = h ? a[u][2] : a[u][0];
            float mine1 = h ? a[u][3] : a[u][1];
            float c0 = mine0 + got0;
            float c1 = mine1 + got1;

            float ao0  = CO2 * s2c[0];
            float ns10 = fmaf(R2, s1c[0], c0);
            s1c[0] = ns10;
            s2c[0] = fmaf(R2, s2c[0], R2 * ns10);
            float mv0 = fmaf(CRF, s2d[0], ao0);
            unsigned b0 = (mv0 >= 40.f) ? 1u : 0u;
            float sp0 = (float)b0;
            float nd10 = fmaf(R2, s1d[0], sp0);
            s1d[0] = nd10;
            s2d[0] = fmaf(R2, s2d[0], R2 * nd10);
            cm0 |= b0 << u;

            float ao1  = CO2 * s2c[1];
            float ns11 = fmaf(R2, s1c[1], c1);
            s1c[1] = ns11;
            s2c[1] = fmaf(R2, s2c[1], R2 * ns11);
            float mv1 = fmaf(CRF, s2d[1], ao1);
            unsigned b1 = (mv1 >= 40.f) ? 1u : 0u;
            float sp1 = (float)b1;
            float nd11 = fmaf(R2, s1d[1], sp1);
            s1d[1] = nd11;
            s2d[1] = fmaf(R2, s2d[1], R2 * nd11);
            cm1 |= b1 << u;
        }
        om[0] |= (unsigned long long)cm0 << t0;
        om[1] |= (unsigned long long)cm1 << t0;
    }

    // stash masks, then coalesced output expansion
    oml[px * 4 + 2 * h]     = om[0];
    oml[px * 4 + 2 * h + 1] = om[1];
    __syncthreads();

    for (int i = tid; i < 128 * 4 * 25; i += 256) {
        int pc = i / 25;                 // (pixel, channel) 0..511
        int j  = i - pc * 25;
        int p  = pc >> 2, c = pc & 3;
        unsigned long long m = oml[pc];
        int py2 = p >> 4, px2 = p & 15;
        int k = 2 * j;
        float2 v;
        v.x = (float)((unsigned)(m >> k) & 1u);
        v.y = (float)((unsigned)(m >> (k + 1)) & 1u);
        float* o = out + ((size_t)(((n * 4 + c) << 14) + (Y0 + py2) * 128 + X0 + px2)) * 50;
        *(float2*)(o + k) = v;
    }
}

// ---------------- fallback (ws too small): R6 single fused kernel ----------------
#define TW   16
#define TH   8
#define R1S  (TW + 6)
#define R1R  (TH + 6)
#define R1N  (R1S * R1R)
#define R2S  (TW + 2)
#define R2R  (TH + 2)
#define R2N  (R2S * R2R)

__global__ __launch_bounds__(256)
void snn_fused_fb(const float* __restrict__ xin,
                  const float* __restrict__ w1,
                  const float* __restrict__ w2,
                  float* __restrict__ out)
{
    __shared__ __align__(16) uint2    xm[4][R1N];
    __shared__ unsigned               s1m[4][R2N];
    __shared__ __align__(16) float    wL1[400];
    __shared__ __align__(16) float    wL2[144];

    const int tid = threadIdx.x;
    const int n   = blockIdx.z;
    const int Y0  = blockIdx.y * TH;
    const int X0  = blockIdx.x * TW;

    for (int i = tid; i < 400; i += 256) {
        int oc = i & 3, r = i >> 2;
        int ic = r / 25, r2 = r - ic * 25;
        int dy = r2 / 5, dx = r2 - dy * 5;
        wL1[i] = w1[((oc * 4 + ic) * 5 + dy) * 5 + dx];
    }
    if (tid < 144) {
        int oc = tid & 3, r = tid >> 2;
        int ic = r / 9, r2 = r - ic * 9;
        int dy = r2 / 3, dx = r2 - dy * 3;
        wL2[tid] = w2[((oc * 4 + ic) * 3 + dy) * 3 + dx];
    }
#pragma unroll
    for (int s = 0; s < 2; ++s) {
        int hp = tid + s * 256;
        if (hp < R1N) {
            int hy = hp / R1S, hx = hp - hy * R1S;
            int gy = Y0 + hy - 3, gx = X0 + hx - 3;
            bool inimg = gy >= 0 && gy < 128 && gx >= 0 && gx < 128;
#pragma unroll
            for (int c = 0; c < 4; ++c) {
                unsigned m0 = 0, m1 = 0;
                if (inimg) {
                    const float2* p = (const float2*)
                        (xin + ((size_t)(((n * 4 + c) * 128 + gy) * 128 + gx)) * 50);
#pragma unroll
                    for (int j = 0; j < 25; ++j) {
                        float2 v = p[j];
                        unsigned b0 = (v.x != 0.f) ? 1u : 0u;
                        unsigned b1 = (v.y != 0.f) ? 1u : 0u;
                        int k = 2 * j;
                        if (k < 32) m0 |= (b0 << k) | (b1 << (k + 1));
                        else        m1 |= (b0 << (k - 32)) | (b1 << (k - 31));
                    }
                }
                xm[c][hp] = make_uint2(m0, m1);
            }
        }
    }
    const bool cw = (tid < R2N);
    const int cy = tid / R2S;
    const int cx = tid - cy * R2S;
    const bool cin = cw && (Y0 + cy - 1) >= 0 && (Y0 + cy - 1) < 128
                        && (X0 + cx - 1) >= 0 && (X0 + cx - 1) < 128;
    const int xbase = cy * R1S + cx;
    const bool iw = (tid < TW * TH);
    const int iy = tid >> 4, ix = tid & 15;
    const int ibase = iy * R2S + ix;

    float s1a[4] = {}, s2a[4] = {}, s1b[4] = {}, s2b[4] = {};
    float s1c[4] = {}, s2c[4] = {}, s1d[4] = {}, s2d[4] = {};
    unsigned long long om[4] = {};

    const float R1  = 0.36787944117144233f;
    const float CO1 = 2.7182818284590452f;
    const float R2  = 0.60653065971263342f;
    const float CO2 = 1.3591409142295226f;
    const float CRF = -54.365636569180902f;

    __syncthreads();

    for (int chk = 0; chk < 5; ++chk) {
        const int t0 = chk * TC;
        if (cw) {
            float a[TC][4];
#pragma unroll
            for (int u = 0; u < TC; ++u) { a[u][0]=0.f; a[u][1]=0.f; a[u][2]=0.f; a[u][3]=0.f; }
            if (cin) {
#pragma unroll 1
                for (int ic = 0; ic < 4; ++ic) {
                    const uint2*  xp = &xm[ic][xbase];
                    const float4* wp = (const float4*)&wL1[ic * 100];
#pragma unroll 1
                    for (int dy = 0; dy < 5; ++dy) {
#pragma unroll
                        for (int dx = 0; dx < 5; ++dx) {
                            uint2 m = xp[dx];
                            unsigned long long mm =
                                ((unsigned long long)m.y << 32) | m.x;
                            unsigned win = (unsigned)(mm >> t0);
                            float4 w = wp[dx];
#pragma unroll
                            for (int u = 0; u < TC; ++u) {
                                float f = (float)((win >> u) & 1u);
                                a[u][0] = fmaf(f, w.x, a[u][0]);
                                a[u][1] = fmaf(f, w.y, a[u][1]);
                                a[u][2] = fmaf(f, w.z, a[u][2]);
                                a[u][3] = fmaf(f, w.w, a[u][3]);
                            }
                        }
                        xp += R1S; wp += 5;
                    }
                }
            }
            unsigned cm[4] = {0, 0, 0, 0};
#pragma unroll
            for (int u = 0; u < TC; ++u) {
#pragma unroll
                for (int oc = 0; oc < 4; ++oc) {
                    float ao  = CO1 * s2a[oc];
                    float ns1 = fmaf(R1, s1a[oc], a[u][oc]);
                    s1a[oc] = ns1;
                    s2a[oc] = fmaf(R1, s2a[oc], R1 * ns1);
                    float mv = fmaf(CRF, s2b[oc], ao);
                    unsigned b = (mv >= 20.f) ? 1u : 0u;
                    float spf = (float)b;
                    float nb1 = fmaf(R1, s1b[oc], spf);
                    s1b[oc] = nb1;
                    s2b[oc] = fmaf(R1, s2b[oc], R1 * nb1);
                    cm[oc] |= b << u;
                }
            }
            s1m[0][tid] = cm[0];
            s1m[1][tid] = cm[1];
            s1m[2][tid] = cm[2];
            s1m[3][tid] = cm[3];
        }
        __syncthreads();
        if (iw) {
            float a[TC][4];
#pragma unroll
            for (int u = 0; u < TC; ++u) { a[u][0]=0.f; a[u][1]=0.f; a[u][2]=0.f; a[u][3]=0.f; }
#pragma unroll 1
            for (int ic = 0; ic < 4; ++ic) {
                const unsigned* sp = &s1m[ic][ibase];
                const float4*   wp = (const float4*)&wL2[ic * 36];
#pragma unroll 1
                for (int dy = 0; dy < 3; ++dy) {
#pragma unroll
                    for (int dx = 0; dx < 3; ++dx) {
                        unsigned win = sp[dx];
                        float4 w = wp[dx];
#pragma unroll
                        for (int u = 0; u < TC; ++u) {
                            float f = (float)((win >> u) & 1u);
                            a[u][0] = fmaf(f, w.x, a[u][0]);
                            a[u][1] = fmaf(f, w.y, a[u][1]);
                            a[u][2] = fmaf(f, w.z, a[u][2]);
                            a[u][3] = fmaf(f, w.w, a[u][3]);
                        }
                    }
                    sp += R2S; wp += 3;
                }
            }
            unsigned cm[4] = {0, 0, 0, 0};
#pragma unroll
            for (int u = 0; u < TC; ++u) {
#pragma unroll
                for (int oc = 0; oc < 4; ++oc) {
                    float ao  = CO2 * s2c[oc];
                    float ns1 = fmaf(R2, s1c[oc], a[u][oc]);
                    s1c[oc] = ns1;
                    s2c[oc] = fmaf(R2, s2c[oc], R2 * ns1);
                    float mv = fmaf(CRF, s2d[oc], ao);
                    unsigned b = (mv >= 40.f) ? 1u : 0u;
                    float spf = (float)b;
                    float nd1 = fmaf(R2, s1d[oc], spf);
                    s1d[oc] = nd1;
                    s2d[oc] = fmaf(R2, s2d[oc], R2 * nd1);
                    cm[oc] |= b << u;
                }
            }
#pragma unroll
            for (int oc = 0; oc < 4; ++oc)
                om[oc] |= (unsigned long long)cm[oc] << t0;
        }
        __syncthreads();
    }
    if (iw) {
#pragma unroll
        for (int c = 0; c < 4; ++c) {
            float* p = out + ((size_t)(((n * 4 + c) * 128 + (Y0 + iy)) * 128 + (X0 + ix))) * 50;
            unsigned long long m = om[c];
#pragma unroll
            for (int j = 0; j < 25; ++j) {
                int k = 2 * j;
                float2 v;
                v.x = (float)((unsigned)(m >> k) & 1u);
                v.y = (float)((unsigned)(m >> (k + 1)) & 1u);
                *(float2*)(p + k) = v;
            }
        }
    }
}

extern "C" void kernel_launch(void* const* d_in, const int* in_sizes, int n_in,
                              void* d_out, int out_size, void* d_ws, size_t ws_size,
                              hipStream_t stream) {
    (void)in_sizes; (void)n_in; (void)out_size;
    const float* x  = (const float*)d_in[0];
    const float* w1 = (const float*)d_in[1];
    const float* w2 = (const float*)d_in[2];
    float* o = (float*)d_out;

    if (ws_size >= 2u * 4194304u) {
        uint2* xmg = (uint2*)d_ws;            // 4 MB, [n][c][yx]
        uint2* s1g = xmg + 524288;            // 4 MB, [n][c][yx]
        hipLaunchKernelGGL(snn_pack, dim3(2048), dim3(256), 0, stream, x, xmg);
        hipLaunchKernelGGL(snn_l1, dim3(8, 16, 8), dim3(256), 0, stream, xmg, w1, s1g);
        hipLaunchKernelGGL(snn_l2, dim3(8, 16, 8), dim3(256), 0, stream, s1g, w2, o);
    } else {
        dim3 grid(128 / TW, 128 / TH, 8);
        hipLaunchKernelGGL(snn_fused_fb, grid, dim3(256), 0, stream, x, w1, w2, o);
    }
}

// Round 10
// 321.952 us; speedup vs baseline: 1.0136x; 1.0088x over previous
//
#include <hip/hip_runtime.h>

// SLAYER 2-layer SNN forward — 3-kernel bitmask pipeline (R10).
// R9 lesson: l1 is VALU-ISSUE-COUNT bound (2->4 waves/SIMD changed nothing;
// VALUBusy ~79%). R10 cuts instructions: packed fp32 (v_pk_fma_f32 via
// float2 ext-vector + __builtin_elementwise_fma) in conv inner loop
// (6 -> 4 instr per tap-timestep) and recurrence (packed 2-oc chain), plus
// dual oc-pair-swapped weight copies in LDS to kill per-u cndmask selects.
// Per-lane arithmetic is op-for-op identical to the passing R9 kernel.

#define TC 10   // timesteps per chunk (50 = 5 chunks)

typedef float v2f __attribute__((ext_vector_type(2)));
#define PKFMA(A, B, C) __builtin_elementwise_fma((A), (B), (C))

// ---------------- kernel A: ballot pack: spikes -> uint2 masks ----------------
__global__ __launch_bounds__(256)
void snn_pack(const float* __restrict__ xin, uint2* __restrict__ xmg)
{
    __shared__ unsigned long long bal[4][50];
    const int tid  = threadIdx.x;
    const int lane = tid & 63;
    const int ws   = tid >> 6;
    const size_t wpx = ((size_t)blockIdx.x * 4 + ws) * 64;
    const float* src = xin + wpx * 50;
#pragma unroll 1
    for (int j = 0; j < 50; ++j) {
        float v = src[j * 64 + lane];            // coalesced 256B / wave-instr
        unsigned long long b = __ballot(v != 0.f);
        if (lane == 0) bal[ws][j] = b;
    }
    __syncthreads();
    const int bitpos = lane * 50;
    const int w = bitpos >> 6, s = bitpos & 63;
    unsigned long long m = bal[ws][w] >> s;
    if (s > 14) m |= bal[ws][w + 1] << (64 - s);
    m &= (1ull << 50) - 1;
    xmg[wpx + lane] = make_uint2((unsigned)m, (unsigned)(m >> 32));
}

// ---------------- kernel B: layer 1 (conv5x5 + psp + spike) ----------------
// 16x8 tile, 2 threads/pixel: h = tid&1 convolves ic {2h,2h+1} and finishes
// oc {2h,2h+1}. Weight copy h has its "mine" oc-pair in the low half.
#define HW1 20
#define HH1 12
#define HP1 21
__global__ __launch_bounds__(256)
void snn_l1(const uint2* __restrict__ xmg, const float* __restrict__ w1,
            uint2* __restrict__ s1g)
{
    __shared__ __align__(16) uint2 xs[4][HH1 * HP1];
    __shared__ __align__(16) float wL1s[800];   // [copy][ic][dy][dx][oc-pairs]

    const int tid = threadIdx.x;
    const int n = blockIdx.z, Y0 = blockIdx.y * 8, X0 = blockIdx.x * 16;

    for (int i = tid; i < 800; i += 256) {
        int cpy = (i >= 400) ? 1 : 0;
        int j = i - cpy * 400;
        int s = j & 3, r = j >> 2;
        int ic = r / 25, r2 = r - ic * 25;
        int dy = r2 / 5, dx = r2 - dy * 5;
        int oc = cpy ? (s ^ 2) : s;
        wL1s[i] = w1[((oc * 4 + ic) * 5 + dy) * 5 + dx];
    }
    if (tid < HW1 * HH1) {
        int hy = tid / HW1, hx = tid - hy * HW1;
        int gy = Y0 + hy - 2, gx = X0 + hx - 2;
        bool ok = gy >= 0 && gy < 128 && gx >= 0 && gx < 128;
        int gi = (gy << 7) + gx;
        int li = hy * HP1 + hx;
#pragma unroll
        for (int c = 0; c < 4; ++c) {
            uint2 v = make_uint2(0u, 0u);
            if (ok) v = xmg[(((size_t)(n * 4 + c)) << 14) + gi];
            xs[c][li] = v;
        }
    }
    __syncthreads();

    const int h  = tid & 1;
    const int px = tid >> 1;
    const int py = px >> 4, pxx = px & 15;
    const int base = py * HP1 + pxx;
    const float* wbase = &wL1s[h * 400];

    v2f s1a = {0.f, 0.f}, s2a = {0.f, 0.f}, s1b = {0.f, 0.f}, s2b = {0.f, 0.f};
    unsigned long long om0 = 0, om1 = 0;
    const v2f R1v  = {0.36787944117144233f, 0.36787944117144233f};  // exp(-1)
    const v2f CO1v = {2.7182818284590452f, 2.7182818284590452f};    // e
    const v2f CRFv = {-54.365636569180902f, -54.365636569180902f};  // -20e

    for (int chk = 0; chk < 5; ++chk) {
        const int t0 = chk * TC;
        v2f am[TC], at[TC];                  // mine / theirs oc-pair partials
#pragma unroll
        for (int u = 0; u < TC; ++u) { am[u] = (v2f){0.f, 0.f}; at[u] = (v2f){0.f, 0.f}; }
#pragma unroll 1
        for (int icl = 0; icl < 2; ++icl) {
            const int ic = 2 * h + icl;
            const uint2*  xp = &xs[ic][base];
            const float4* wp = (const float4*)(wbase + ic * 100);
#pragma unroll 1
            for (int dy = 0; dy < 5; ++dy) {
#pragma unroll
                for (int dx = 0; dx < 5; ++dx) {
                    uint2 mv = xp[dx];
                    unsigned long long mm = ((unsigned long long)mv.y << 32) | mv.x;
                    unsigned win = (unsigned)(mm >> t0);
                    float4 w = wp[dx];
                    v2f wm = {w.x, w.y}, wt = {w.z, w.w};
#pragma unroll
                    for (int u = 0; u < TC; ++u) {
                        float f = (float)((win >> u) & 1u);
                        v2f ff = {f, f};
                        am[u] = PKFMA(ff, wm, am[u]);
                        at[u] = PKFMA(ff, wt, at[u]);
                    }
                }
                xp += HP1; wp += 5;
            }
        }
        unsigned cm0 = 0, cm1 = 0;
#pragma unroll
        for (int u = 0; u < TC; ++u) {
            v2f got;
            got.x = __shfl_xor(at[u].x, 1);
            got.y = __shfl_xor(at[u].y, 1);
            v2f c = am[u] + got;             // self ic-pair + partner ic-pair
            v2f ao  = CO1v * s2a;
            v2f ns1 = PKFMA(R1v, s1a, c);
            s1a = ns1;
            s2a = PKFMA(R1v, s2a, R1v * ns1);
            v2f mvv = PKFMA(CRFv, s2b, ao);
            unsigned b0 = (mvv.x >= 20.f) ? 1u : 0u;
            unsigned b1 = (mvv.y >= 20.f) ? 1u : 0u;
            v2f sp = {(float)b0, (float)b1};
            v2f nb1 = PKFMA(R1v, s1b, sp);
            s1b = nb1;
            s2b = PKFMA(R1v, s2b, R1v * nb1);
            cm0 |= b0 << u;
            cm1 |= b1 << u;
        }
        om0 |= (unsigned long long)cm0 << t0;
        om1 |= (unsigned long long)cm1 << t0;
    }

    const int yx = (Y0 + py) * 128 + X0 + pxx;
    s1g[(((size_t)(n * 4 + 2 * h)) << 14) + yx] =
        make_uint2((unsigned)om0, (unsigned)(om0 >> 32));
    s1g[(((size_t)(n * 4 + 2 * h + 1)) << 14) + yx] =
        make_uint2((unsigned)om1, (unsigned)(om1 >> 32));
}

// ---------------- kernel C: layer 2 (conv3x3 + psp + spike) + expand ----------------
#define HW2 18
#define HH2 10
#define HP2 19
__global__ __launch_bounds__(256)
void snn_l2(const uint2* __restrict__ s1g, const float* __restrict__ w2,
            float* __restrict__ out)
{
    __shared__ __align__(16) uint2 ss[4][HH2 * HP2];
    __shared__ __align__(16) float wL2s[288];   // [copy][ic][dy][dx][oc-pairs]
    __shared__ unsigned long long oml[128 * 4];

    const int tid = threadIdx.x;
    const int n = blockIdx.z, Y0 = blockIdx.y * 8, X0 = blockIdx.x * 16;

    for (int i = tid; i < 288; i += 256) {
        int cpy = (i >= 144) ? 1 : 0;
        int j = i - cpy * 144;
        int s = j & 3, r = j >> 2;
        int ic = r / 9, r2 = r - ic * 9;
        int dy = r2 / 3, dx = r2 - dy * 3;
        int oc = cpy ? (s ^ 2) : s;
        wL2s[i] = w2[((oc * 4 + ic) * 3 + dy) * 3 + dx];
    }
    if (tid < HW2 * HH2) {
        int hy = tid / HW2, hx = tid - hy * HW2;
        int gy = Y0 + hy - 1, gx = X0 + hx - 1;
        bool ok = gy >= 0 && gy < 128 && gx >= 0 && gx < 128;
        int gi = (gy << 7) + gx;
        int li = hy * HP2 + hx;
#pragma unroll
        for (int c = 0; c < 4; ++c) {
            uint2 v = make_uint2(0u, 0u);
            if (ok) v = s1g[(((size_t)(n * 4 + c)) << 14) + gi];
            ss[c][li] = v;
        }
    }
    __syncthreads();

    const int h  = tid & 1;
    const int px = tid >> 1;
    const int py = px >> 4, pxx = px & 15;
    const int base = py * HP2 + pxx;
    const float* wbase = &wL2s[h * 144];

    v2f s1c = {0.f, 0.f}, s2c = {0.f, 0.f}, s1d = {0.f, 0.f}, s2d = {0.f, 0.f};
    unsigned long long om0 = 0, om1 = 0;
    const v2f R2v  = {0.60653065971263342f, 0.60653065971263342f};  // exp(-1/2)
    const v2f CO2v = {1.3591409142295226f, 1.3591409142295226f};    // e/2
    const v2f CRFv = {-54.365636569180902f, -54.365636569180902f};  // -40e/2

    for (int chk = 0; chk < 5; ++chk) {
        const int t0 = chk * TC;
        v2f am[TC], at[TC];
#pragma unroll
        for (int u = 0; u < TC; ++u) { am[u] = (v2f){0.f, 0.f}; at[u] = (v2f){0.f, 0.f}; }
#pragma unroll 1
        for (int icl = 0; icl < 2; ++icl) {
            const int ic = 2 * h + icl;
            const uint2*  sp = &ss[ic][base];
            const float4* wp = (const float4*)(wbase + ic * 36);
#pragma unroll 1
            for (int dy = 0; dy < 3; ++dy) {
#pragma unroll
                for (int dx = 0; dx < 3; ++dx) {
                    uint2 mv = sp[dx];
                    unsigned long long mm = ((unsigned long long)mv.y << 32) | mv.x;
                    unsigned win = (unsigned)(mm >> t0);
                    float4 w = wp[dx];
                    v2f wm = {w.x, w.y}, wt = {w.z, w.w};
#pragma unroll
                    for (int u = 0; u < TC; ++u) {
                        float f = (float)((win >> u) & 1u);
                        v2f ff = {f, f};
                        am[u] = PKFMA(ff, wm, am[u]);
                        at[u] = PKFMA(ff, wt, at[u]);
                    }
                }
                sp += HP2; wp += 3;
            }
        }
        unsigned cm0 = 0, cm1 = 0;
#pragma unroll
        for (int u = 0; u < TC; ++u) {
            v2f got;
            got.x = __shfl_xor(at[u].x, 1);
            got.y = __shfl_xor(at[u].y, 1);
            v2f c = am[u] + got;
            v2f ao  = CO2v * s2c;
            v2f ns1 = PKFMA(R2v, s1c, c);
            s1c = ns1;
            s2c = PKFMA(R2v, s2c, R2v * ns1);
            v2f mvv = PKFMA(CRFv, s2d, ao);
            unsigned b0 = (mvv.x >= 40.f) ? 1u : 0u;
            unsigned b1 = (mvv.y >= 40.f) ? 1u : 0u;
            v2f sp2 = {(float)b0, (float)b1};
            v2f nd1 = PKFMA(R2v, s1d, sp2);
            s1d = nd1;
            s2d = PKFMA(R2v, s2d, R2v * nd1);
            cm0 |= b0 << u;
            cm1 |= b1 << u;
        }
        om0 |= (unsigned long long)cm0 << t0;
        om1 |= (unsigned long long)cm1 << t0;
    }

    oml[px * 4 + 2 * h]     = om0;
    oml[px * 4 + 2 * h + 1] = om1;
    __syncthreads();

    for (int i = tid; i < 128 * 4 * 25; i += 256) {
        int pc = i / 25;
        int j  = i - pc * 25;
        int p  = pc >> 2, c = pc & 3;
        unsigned long long m = oml[pc];
        int py2 = p >> 4, px2 = p & 15;
        int k = 2 * j;
        float2 v;
        v.x = (float)((unsigned)(m >> k) & 1u);
        v.y = (float)((unsigned)(m >> (k + 1)) & 1u);
        float* o = out + ((size_t)(((n * 4 + c) << 14) + (Y0 + py2) * 128 + X0 + px2)) * 50;
        *(float2*)(o + k) = v;
    }
}

// ---------------- fallback (ws too small): R6 single fused kernel ----------------
#define TW   16
#define TH   8
#define R1S  (TW + 6)
#define R1R  (TH + 6)
#define R1N  (R1S * R1R)
#define R2S  (TW + 2)
#define R2R  (TH + 2)
#define R2N  (R2S * R2R)

__global__ __launch_bounds__(256)
void snn_fused_fb(const float* __restrict__ xin,
                  const float* __restrict__ w1,
                  const float* __restrict__ w2,
                  float* __restrict__ out)
{
    __shared__ __align__(16) uint2    xm[4][R1N];
    __shared__ unsigned               s1m[4][R2N];
    __shared__ __align__(16) float    wL1[400];
    __shared__ __align__(16) float    wL2[144];

    const int tid = threadIdx.x;
    const int n   = blockIdx.z;
    const int Y0  = blockIdx.y * TH;
    const int X0  = blockIdx.x * TW;

    for (int i = tid; i < 400; i += 256) {
        int oc = i & 3, r = i >> 2;
        int ic = r / 25, r2 = r - ic * 25;
        int dy = r2 / 5, dx = r2 - dy * 5;
        wL1[i] = w1[((oc * 4 + ic) * 5 + dy) * 5 + dx];
    }
    if (tid < 144) {
        int oc = tid & 3, r = tid >> 2;
        int ic = r / 9, r2 = r - ic * 9;
        int dy = r2 / 3, dx = r2 - dy * 3;
        wL2[tid] = w2[((oc * 4 + ic) * 3 + dy) * 3 + dx];
    }
#pragma unroll
    for (int s = 0; s < 2; ++s) {
        int hp = tid + s * 256;
        if (hp < R1N) {
            int hy = hp / R1S, hx = hp - hy * R1S;
            int gy = Y0 + hy - 3, gx = X0 + hx - 3;
            bool inimg = gy >= 0 && gy < 128 && gx >= 0 && gx < 128;
#pragma unroll
            for (int c = 0; c < 4; ++c) {
                unsigned m0 = 0, m1 = 0;
                if (inimg) {
                    const float2* p = (const float2*)
                        (xin + ((size_t)(((n * 4 + c) * 128 + gy) * 128 + gx)) * 50);
#pragma unroll
                    for (int j = 0; j < 25; ++j) {
                        float2 v = p[j];
                        unsigned b0 = (v.x != 0.f) ? 1u : 0u;
                        unsigned b1 = (v.y != 0.f) ? 1u : 0u;
                        int k = 2 * j;
                        if (k < 32) m0 |= (b0 << k) | (b1 << (k + 1));
                        else        m1 |= (b0 << (k - 32)) | (b1 << (k - 31));
                    }
                }
                xm[c][hp] = make_uint2(m0, m1);
            }
        }
    }
    const bool cw = (tid < R2N);
    const int cy = tid / R2S;
    const int cx = tid - cy * R2S;
    const bool cin = cw && (Y0 + cy - 1) >= 0 && (Y0 + cy - 1) < 128
                        && (X0 + cx - 1) >= 0 && (X0 + cx - 1) < 128;
    const int xbase = cy * R1S + cx;
    const bool iw = (tid < TW * TH);
    const int iy = tid >> 4, ix = tid & 15;
    const int ibase = iy * R2S + ix;

    float s1a[4] = {}, s2a[4] = {}, s1b[4] = {}, s2b[4] = {};
    float s1c[4] = {}, s2c[4] = {}, s1d[4] = {}, s2d[4] = {};
    unsigned long long om[4] = {};

    const float R1  = 0.36787944117144233f;
    const float CO1 = 2.7182818284590452f;
    const float R2  = 0.60653065971263342f;
    const float CO2 = 1.3591409142295226f;
    const float CRF = -54.365636569180902f;

    __syncthreads();

    for (int chk = 0; chk < 5; ++chk) {
        const int t0 = chk * TC;
        if (cw) {
            float a[TC][4];
#pragma unroll
            for (int u = 0; u < TC; ++u) { a[u][0]=0.f; a[u][1]=0.f; a[u][2]=0.f; a[u][3]=0.f; }
            if (cin) {
#pragma unroll 1
                for (int ic = 0; ic < 4; ++ic) {
                    const uint2*  xp = &xm[ic][xbase];
                    const float4* wp = (const float4*)&wL1[ic * 100];
#pragma unroll 1
                    for (int dy = 0; dy < 5; ++dy) {
#pragma unroll
                        for (int dx = 0; dx < 5; ++dx) {
                            uint2 m = xp[dx];
                            unsigned long long mm =
                                ((unsigned long long)m.y << 32) | m.x;
                            unsigned win = (unsigned)(mm >> t0);
                            float4 w = wp[dx];
#pragma unroll
                            for (int u = 0; u < TC; ++u) {
                                float f = (float)((win >> u) & 1u);
                                a[u][0] = fmaf(f, w.x, a[u][0]);
                                a[u][1] = fmaf(f, w.y, a[u][1]);
                                a[u][2] = fmaf(f, w.z, a[u][2]);
                                a[u][3] = fmaf(f, w.w, a[u][3]);
                            }
                        }
                        xp += R1S; wp += 5;
                    }
                }
            }
            unsigned cm[4] = {0, 0, 0, 0};
#pragma unroll
            for (int u = 0; u < TC; ++u) {
#pragma unroll
                for (int oc = 0; oc < 4; ++oc) {
                    float ao  = CO1 * s2a[oc];
                    float ns1 = fmaf(R1, s1a[oc], a[u][oc]);
                    s1a[oc] = ns1;
                    s2a[oc] = fmaf(R1, s2a[oc], R1 * ns1);
                    float mv = fmaf(CRF, s2b[oc], ao);
                    unsigned b = (mv >= 20.f) ? 1u : 0u;
                    float spf = (float)b;
                    float nb1 = fmaf(R1, s1b[oc], spf);
                    s1b[oc] = nb1;
                    s2b[oc] = fmaf(R1, s2b[oc], R1 * nb1);
                    cm[oc] |= b << u;
                }
            }
            s1m[0][tid] = cm[0];
            s1m[1][tid] = cm[1];
            s1m[2][tid] = cm[2];
            s1m[3][tid] = cm[3];
        }
        __syncthreads();
        if (iw) {
            float a[TC][4];
#pragma unroll
            for (int u = 0; u < TC; ++u) { a[u][0]=0.f; a[u][1]=0.f; a[u][2]=0.f; a[u][3]=0.f; }
#pragma unroll 1
            for (int ic = 0; ic < 4; ++ic) {
                const unsigned* sp = &s1m[ic][ibase];
                const float4*   wp = (const float4*)&wL2[ic * 36];
#pragma unroll 1
                for (int dy = 0; dy < 3; ++dy) {
#pragma unroll
                    for (int dx = 0; dx < 3; ++dx) {
                        unsigned win = sp[dx];
                        float4 w = wp[dx];
#pragma unroll
                        for (int u = 0; u < TC; ++u) {
                            float f = (float)((win >> u) & 1u);
                            a[u][0] = fmaf(f, w.x, a[u][0]);
                            a[u][1] = fmaf(f, w.y, a[u][1]);
                            a[u][2] = fmaf(f, w.z, a[u][2]);
                            a[u][3] = fmaf(f, w.w, a[u][3]);
                        }
                    }
                    sp += R2S; wp += 3;
                }
            }
            unsigned cm[4] = {0, 0, 0, 0};
#pragma unroll
            for (int u = 0; u < TC; ++u) {
#pragma unroll
                for (int oc = 0; oc < 4; ++oc) {
                    float ao  = CO2 * s2c[oc];
                    float ns1 = fmaf(R2, s1c[oc], a[u][oc]);
                    s1c[oc] = ns1;
                    s2c[oc] = fmaf(R2, s2c[oc], R2 * ns1);
                    float mv = fmaf(CRF, s2d[oc], ao);
                    unsigned b = (mv >= 40.f) ? 1u : 0u;
                    float spf = (float)b;
                    float nd1 = fmaf(R2, s1d[oc], spf);
                    s1d[oc] = nd1;
                    s2d[oc] = fmaf(R2, s2d[oc], R2 * nd1);
                    cm[oc] |= b << u;
                }
            }
#pragma unroll
            for (int oc = 0; oc < 4; ++oc)
                om[oc] |= (unsigned long long)cm[oc] << t0;
        }
        __syncthreads();
    }
    if (iw) {
#pragma unroll
        for (int c = 0; c < 4; ++c) {
            float* p = out + ((size_t)(((n * 4 + c) * 128 + (Y0 + iy)) * 128 + (X0 + ix))) * 50;
            unsigned long long m = om[c];
#pragma unroll
            for (int j = 0; j < 25; ++j) {
                int k = 2 * j;
                float2 v;
                v.x = (float)((unsigned)(m >> k) & 1u);
                v.y = (float)((unsigned)(m >> (k + 1)) & 1u);
                *(float2*)(p + k) = v;
            }
        }
    }
}

extern "C" void kernel_launch(void* const* d_in, const int* in_sizes, int n_in,
                              void* d_out, int out_size, void* d_ws, size_t ws_size,
                              hipStream_t stream) {
    (void)in_sizes; (void)n_in; (void)out_size;
    const float* x  = (const float*)d_in[0];
    const float* w1 = (const float*)d_in[1];
    const float* w2 = (const float*)d_in[2];
    float* o = (float*)d_out;

    if (ws_size >= 2u * 4194304u) {
        uint2* xmg = (uint2*)d_ws;            // 4 MB, [n][c][yx]
        uint2* s1g = xmg + 524288;            // 4 MB, [n][c][yx]
        hipLaunchKernelGGL(snn_pack, dim3(2048), dim3(256), 0, stream, x, xmg);
        hipLaunchKernelGGL(snn_l1, dim3(8, 16, 8), dim3(256), 0, stream, xmg, w1, s1g);
        hipLaunchKernelGGL(snn_l2, dim3(8, 16, 8), dim3(256), 0, stream, s1g, w2, o);
    } else {
        dim3 grid(128 / TW, 128 / TH, 8);
        hipLaunchKernelGGL(snn_fused_fb, grid, dim3(256), 0, stream, x, w1, w2, o);
    }
}

// Round 11
// 321.919 us; speedup vs baseline: 1.0137x; 1.0001x over previous
//
#include <hip/hip_runtime.h>

// SLAYER 2-layer SNN forward — 3-kernel bitmask pipeline (R11).
// R10 lesson: MI355X has NO double-rate packed fp32 (157.3 TF = 1 FMA/lane/cyc
// total), so v_pk_fma was a guaranteed null. Conv FMA floor ~45us chip-wide.
// R11 targets the two proven inefficiencies:
//   (a) pack was latency-bound by '#pragma unroll 1' (1 outstanding load,
//       50 serial iters) -> unroll 10, BW-bound.
//   (b) l1/l2 conv: group the whole tap-row's LDS reads into registers before
//       the FMA block so one lgkmcnt wait covers the row (cuts VALU idle).
// Arithmetic identical to passing R9/R10 kernels (absmax 0).

#define TC 10   // timesteps per chunk (50 = 5 chunks)

typedef float v2f __attribute__((ext_vector_type(2)));
#define PKFMA(A, B, C) __builtin_elementwise_fma((A), (B), (C))

// ---------------- kernel A: ballot pack: spikes -> uint2 masks ----------------
__global__ __launch_bounds__(256)
void snn_pack(const float* __restrict__ xin, uint2* __restrict__ xmg)
{
    __shared__ unsigned long long bal[4][50];
    const int tid  = threadIdx.x;
    const int lane = tid & 63;
    const int ws   = tid >> 6;
    const size_t wpx = ((size_t)blockIdx.x * 4 + ws) * 64;
    const float* src = xin + wpx * 50;
#pragma unroll 10
    for (int j = 0; j < 50; ++j) {
        float v = src[j * 64 + lane];            // coalesced 256B / wave-instr
        unsigned long long b = __ballot(v != 0.f);
        if (lane == 0) bal[ws][j] = b;
    }
    __syncthreads();
    const int bitpos = lane * 50;
    const int w = bitpos >> 6, s = bitpos & 63;
    unsigned long long m = bal[ws][w] >> s;
    if (s > 14) m |= bal[ws][w + 1] << (64 - s);
    m &= (1ull << 50) - 1;
    xmg[wpx + lane] = make_uint2((unsigned)m, (unsigned)(m >> 32));
}

// one tap: window extract + 4 packed FMAs into am/at[u]
#define SNN_TAP(RV, WIDX)                                              \
    {                                                                  \
        unsigned long long mm =                                        \
            ((unsigned long long)(RV).y << 32) | (RV).x;               \
        unsigned win = (unsigned)(mm >> t0);                           \
        float4 w = wp[WIDX];                                           \
        v2f wm = {w.x, w.y}, wt = {w.z, w.w};                          \
        _Pragma("unroll")                                              \
        for (int u = 0; u < TC; ++u) {                                 \
            float f = (float)((win >> u) & 1u);                        \
            v2f ff = {f, f};                                           \
            am[u] = PKFMA(ff, wm, am[u]);                              \
            at[u] = PKFMA(ff, wt, at[u]);                              \
        }                                                              \
    }

// ---------------- kernel B: layer 1 (conv5x5 + psp + spike) ----------------
// 16x8 tile, 2 threads/pixel: h = tid&1 convolves ic {2h,2h+1} and finishes
// oc {2h,2h+1}. Weight copy h has its "mine" oc-pair in the low half.
#define HW1 20
#define HH1 12
#define HP1 21
__global__ __launch_bounds__(256)
void snn_l1(const uint2* __restrict__ xmg, const float* __restrict__ w1,
            uint2* __restrict__ s1g)
{
    __shared__ __align__(16) uint2 xs[4][HH1 * HP1];
    __shared__ __align__(16) float wL1s[800];   // [copy][ic][dy][dx][oc-pairs]

    const int tid = threadIdx.x;
    const int n = blockIdx.z, Y0 = blockIdx.y * 8, X0 = blockIdx.x * 16;

    for (int i = tid; i < 800; i += 256) {
        int cpy = (i >= 400) ? 1 : 0;
        int j = i - cpy * 400;
        int s = j & 3, r = j >> 2;
        int ic = r / 25, r2 = r - ic * 25;
        int dy = r2 / 5, dx = r2 - dy * 5;
        int oc = cpy ? (s ^ 2) : s;
        wL1s[i] = w1[((oc * 4 + ic) * 5 + dy) * 5 + dx];
    }
    if (tid < HW1 * HH1) {
        int hy = tid / HW1, hx = tid - hy * HW1;
        int gy = Y0 + hy - 2, gx = X0 + hx - 2;
        bool ok = gy >= 0 && gy < 128 && gx >= 0 && gx < 128;
        int gi = (gy << 7) + gx;
        int li = hy * HP1 + hx;
#pragma unroll
        for (int c = 0; c < 4; ++c) {
            uint2 v = make_uint2(0u, 0u);
            if (ok) v = xmg[(((size_t)(n * 4 + c)) << 14) + gi];
            xs[c][li] = v;
        }
    }
    __syncthreads();

    const int h  = tid & 1;
    const int px = tid >> 1;
    const int py = px >> 4, pxx = px & 15;
    const int base = py * HP1 + pxx;
    const float* wbase = &wL1s[h * 400];

    v2f s1a = {0.f, 0.f}, s2a = {0.f, 0.f}, s1b = {0.f, 0.f}, s2b = {0.f, 0.f};
    unsigned long long om0 = 0, om1 = 0;
    const v2f R1v  = {0.36787944117144233f, 0.36787944117144233f};  // exp(-1)
    const v2f CO1v = {2.7182818284590452f, 2.7182818284590452f};    // e
    const v2f CRFv = {-54.365636569180902f, -54.365636569180902f};  // -20e

    for (int chk = 0; chk < 5; ++chk) {
        const int t0 = chk * TC;
        v2f am[TC], at[TC];                  // mine / theirs oc-pair partials
#pragma unroll
        for (int u = 0; u < TC; ++u) { am[u] = (v2f){0.f, 0.f}; at[u] = (v2f){0.f, 0.f}; }
#pragma unroll 1
        for (int icl = 0; icl < 2; ++icl) {
            const int ic = 2 * h + icl;
            const uint2*  xp = &xs[ic][base];
            const float4* wp = (const float4*)(wbase + ic * 100);
#pragma unroll 1
            for (int dy = 0; dy < 5; ++dy) {
                // group the row's 5 LDS reads -> one lgkm wait covers all
                uint2 r0 = xp[0], r1 = xp[1], r2 = xp[2], r3 = xp[3], r4 = xp[4];
                SNN_TAP(r0, 0)
                SNN_TAP(r1, 1)
                SNN_TAP(r2, 2)
                SNN_TAP(r3, 3)
                SNN_TAP(r4, 4)
                xp += HP1; wp += 5;
            }
        }
        unsigned cm0 = 0, cm1 = 0;
#pragma unroll
        for (int u = 0; u < TC; ++u) {
            v2f got;
            got.x = __shfl_xor(at[u].x, 1);
            got.y = __shfl_xor(at[u].y, 1);
            v2f c = am[u] + got;             // self ic-pair + partner ic-pair
            v2f ao  = CO1v * s2a;
            v2f ns1 = PKFMA(R1v, s1a, c);
            s1a = ns1;
            s2a = PKFMA(R1v, s2a, R1v * ns1);
            v2f mvv = PKFMA(CRFv, s2b, ao);
            unsigned b0 = (mvv.x >= 20.f) ? 1u : 0u;
            unsigned b1 = (mvv.y >= 20.f) ? 1u : 0u;
            v2f sp = {(float)b0, (float)b1};
            v2f nb1 = PKFMA(R1v, s1b, sp);
            s1b = nb1;
            s2b = PKFMA(R1v, s2b, R1v * nb1);
            cm0 |= b0 << u;
            cm1 |= b1 << u;
        }
        om0 |= (unsigned long long)cm0 << t0;
        om1 |= (unsigned long long)cm1 << t0;
    }

    const int yx = (Y0 + py) * 128 + X0 + pxx;
    s1g[(((size_t)(n * 4 + 2 * h)) << 14) + yx] =
        make_uint2((unsigned)om0, (unsigned)(om0 >> 32));
    s1g[(((size_t)(n * 4 + 2 * h + 1)) << 14) + yx] =
        make_uint2((unsigned)om1, (unsigned)(om1 >> 32));
}

// ---------------- kernel C: layer 2 (conv3x3 + psp + spike) + expand ----------------
#define HW2 18
#define HH2 10
#define HP2 19
__global__ __launch_bounds__(256)
void snn_l2(const uint2* __restrict__ s1g, const float* __restrict__ w2,
            float* __restrict__ out)
{
    __shared__ __align__(16) uint2 ss[4][HH2 * HP2];
    __shared__ __align__(16) float wL2s[288];   // [copy][ic][dy][dx][oc-pairs]
    __shared__ unsigned long long oml[128 * 4];

    const int tid = threadIdx.x;
    const int n = blockIdx.z, Y0 = blockIdx.y * 8, X0 = blockIdx.x * 16;

    for (int i = tid; i < 288; i += 256) {
        int cpy = (i >= 144) ? 1 : 0;
        int j = i - cpy * 144;
        int s = j & 3, r = j >> 2;
        int ic = r / 9, r2 = r - ic * 9;
        int dy = r2 / 3, dx = r2 - dy * 3;
        int oc = cpy ? (s ^ 2) : s;
        wL2s[i] = w2[((oc * 4 + ic) * 3 + dy) * 3 + dx];
    }
    if (tid < HW2 * HH2) {
        int hy = tid / HW2, hx = tid - hy * HW2;
        int gy = Y0 + hy - 1, gx = X0 + hx - 1;
        bool ok = gy >= 0 && gy < 128 && gx >= 0 && gx < 128;
        int gi = (gy << 7) + gx;
        int li = hy * HP2 + hx;
#pragma unroll
        for (int c = 0; c < 4; ++c) {
            uint2 v = make_uint2(0u, 0u);
            if (ok) v = s1g[(((size_t)(n * 4 + c)) << 14) + gi];
            ss[c][li] = v;
        }
    }
    __syncthreads();

    const int h  = tid & 1;
    const int px = tid >> 1;
    const int py = px >> 4, pxx = px & 15;
    const int base = py * HP2 + pxx;
    const float* wbase = &wL2s[h * 144];

    v2f s1c = {0.f, 0.f}, s2c = {0.f, 0.f}, s1d = {0.f, 0.f}, s2d = {0.f, 0.f};
    unsigned long long om0 = 0, om1 = 0;
    const v2f R2v  = {0.60653065971263342f, 0.60653065971263342f};  // exp(-1/2)
    const v2f CO2v = {1.3591409142295226f, 1.3591409142295226f};    // e/2
    const v2f CRFv = {-54.365636569180902f, -54.365636569180902f};  // -40e/2

    for (int chk = 0; chk < 5; ++chk) {
        const int t0 = chk * TC;
        v2f am[TC], at[TC];
#pragma unroll
        for (int u = 0; u < TC; ++u) { am[u] = (v2f){0.f, 0.f}; at[u] = (v2f){0.f, 0.f}; }
#pragma unroll 1
        for (int icl = 0; icl < 2; ++icl) {
            const int ic = 2 * h + icl;
            const uint2*  sp = &ss[ic][base];
            const float4* wp = (const float4*)(wbase + ic * 36);
#pragma unroll 1
            for (int dy = 0; dy < 3; ++dy) {
                uint2 r0 = sp[0], r1 = sp[1], r2 = sp[2];
                SNN_TAP(r0, 0)
                SNN_TAP(r1, 1)
                SNN_TAP(r2, 2)
                sp += HP2; wp += 3;
            }
        }
        unsigned cm0 = 0, cm1 = 0;
#pragma unroll
        for (int u = 0; u < TC; ++u) {
            v2f got;
            got.x = __shfl_xor(at[u].x, 1);
            got.y = __shfl_xor(at[u].y, 1);
            v2f c = am[u] + got;
            v2f ao  = CO2v * s2c;
            v2f ns1 = PKFMA(R2v, s1c, c);
            s1c = ns1;
            s2c = PKFMA(R2v, s2c, R2v * ns1);
            v2f mvv = PKFMA(CRFv, s2d, ao);
            unsigned b0 = (mvv.x >= 40.f) ? 1u : 0u;
            unsigned b1 = (mvv.y >= 40.f) ? 1u : 0u;
            v2f sp2 = {(float)b0, (float)b1};
            v2f nd1 = PKFMA(R2v, s1d, sp2);
            s1d = nd1;
            s2d = PKFMA(R2v, s2d, R2v * nd1);
            cm0 |= b0 << u;
            cm1 |= b1 << u;
        }
        om0 |= (unsigned long long)cm0 << t0;
        om1 |= (unsigned long long)cm1 << t0;
    }

    oml[px * 4 + 2 * h]     = om0;
    oml[px * 4 + 2 * h + 1] = om1;
    __syncthreads();

    for (int i = tid; i < 128 * 4 * 25; i += 256) {
        int pc = i / 25;
        int j  = i - pc * 25;
        int p  = pc >> 2, c = pc & 3;
        unsigned long long m = oml[pc];
        int py2 = p >> 4, px2 = p & 15;
        int k = 2 * j;
        float2 v;
        v.x = (float)((unsigned)(m >> k) & 1u);
        v.y = (float)((unsigned)(m >> (k + 1)) & 1u);
        float* o = out + ((size_t)(((n * 4 + c) << 14) + (Y0 + py2) * 128 + X0 + px2)) * 50;
        *(float2*)(o + k) = v;
    }
}

// ---------------- fallback (ws too small): R6 single fused kernel ----------------
#define TW   16
#define TH   8
#define R1S  (TW + 6)
#define R1R  (TH + 6)
#define R1N  (R1S * R1R)
#define R2S  (TW + 2)
#define R2R  (TH + 2)
#define R2N  (R2S * R2R)

__global__ __launch_bounds__(256)
void snn_fused_fb(const float* __restrict__ xin,
                  const float* __restrict__ w1,
                  const float* __restrict__ w2,
                  float* __restrict__ out)
{
    __shared__ __align__(16) uint2    xm[4][R1N];
    __shared__ unsigned               s1m[4][R2N];
    __shared__ __align__(16) float    wL1[400];
    __shared__ __align__(16) float    wL2[144];

    const int tid = threadIdx.x;
    const int n   = blockIdx.z;
    const int Y0  = blockIdx.y * TH;
    const int X0  = blockIdx.x * TW;

    for (int i = tid; i < 400; i += 256) {
        int oc = i & 3, r = i >> 2;
        int ic = r / 25, r2 = r - ic * 25;
        int dy = r2 / 5, dx = r2 - dy * 5;
        wL1[i] = w1[((oc * 4 + ic) * 5 + dy) * 5 + dx];
    }
    if (tid < 144) {
        int oc = tid & 3, r = tid >> 2;
        int ic = r / 9, r2 = r - ic * 9;
        int dy = r2 / 3, dx = r2 - dy * 3;
        wL2[tid] = w2[((oc * 4 + ic) * 3 + dy) * 3 + dx];
    }
#pragma unroll
    for (int s = 0; s < 2; ++s) {
        int hp = tid + s * 256;
        if (hp < R1N) {
            int hy = hp / R1S, hx = hp - hy * R1S;
            int gy = Y0 + hy - 3, gx = X0 + hx - 3;
            bool inimg = gy >= 0 && gy < 128 && gx >= 0 && gx < 128;
#pragma unroll
            for (int c = 0; c < 4; ++c) {
                unsigned m0 = 0, m1 = 0;
                if (inimg) {
                    const float2* p = (const float2*)
                        (xin + ((size_t)(((n * 4 + c) * 128 + gy) * 128 + gx)) * 50);
#pragma unroll
                    for (int j = 0; j < 25; ++j) {
                        float2 v = p[j];
                        unsigned b0 = (v.x != 0.f) ? 1u : 0u;
                        unsigned b1 = (v.y != 0.f) ? 1u : 0u;
                        int k = 2 * j;
                        if (k < 32) m0 |= (b0 << k) | (b1 << (k + 1));
                        else        m1 |= (b0 << (k - 32)) | (b1 << (k - 31));
                    }
                }
                xm[c][hp] = make_uint2(m0, m1);
            }
        }
    }
    const bool cw = (tid < R2N);
    const int cy = tid / R2S;
    const int cx = tid - cy * R2S;
    const bool cin = cw && (Y0 + cy - 1) >= 0 && (Y0 + cy - 1) < 128
                        && (X0 + cx - 1) >= 0 && (X0 + cx - 1) < 128;
    const int xbase = cy * R1S + cx;
    const bool iw = (tid < TW * TH);
    const int iy = tid >> 4, ix = tid & 15;
    const int ibase = iy * R2S + ix;

    float s1a[4] = {}, s2a[4] = {}, s1b[4] = {}, s2b[4] = {};
    float s1c[4] = {}, s2c[4] = {}, s1d[4] = {}, s2d[4] = {};
    unsigned long long om[4] = {};

    const float R1  = 0.36787944117144233f;
    const float CO1 = 2.7182818284590452f;
    const float R2  = 0.60653065971263342f;
    const float CO2 = 1.3591409142295226f;
    const float CRF = -54.365636569180902f;

    __syncthreads();

    for (int chk = 0; chk < 5; ++chk) {
        const int t0 = chk * TC;
        if (cw) {
            float a[TC][4];
#pragma unroll
            for (int u = 0; u < TC; ++u) { a[u][0]=0.f; a[u][1]=0.f; a[u][2]=0.f; a[u][3]=0.f; }
            if (cin) {
#pragma unroll 1
                for (int ic = 0; ic < 4; ++ic) {
                    const uint2*  xp = &xm[ic][xbase];
                    const float4* wp = (const float4*)&wL1[ic * 100];
#pragma unroll 1
                    for (int dy = 0; dy < 5; ++dy) {
#pragma unroll
                        for (int dx = 0; dx < 5; ++dx) {
                            uint2 m = xp[dx];
                            unsigned long long mm =
                                ((unsigned long long)m.y << 32) | m.x;
                            unsigned win = (unsigned)(mm >> t0);
                            float4 w = wp[dx];
#pragma unroll
                            for (int u = 0; u < TC; ++u) {
                                float f = (float)((win >> u) & 1u);
                                a[u][0] = fmaf(f, w.x, a[u][0]);
                                a[u][1] = fmaf(f, w.y, a[u][1]);
                                a[u][2] = fmaf(f, w.z, a[u][2]);
                                a[u][3] = fmaf(f, w.w, a[u][3]);
                            }
                        }
                        xp += R1S; wp += 5;
                    }
                }
            }
            unsigned cm[4] = {0, 0, 0, 0};
#pragma unroll
            for (int u = 0; u < TC; ++u) {
#pragma unroll
                for (int oc = 0; oc < 4; ++oc) {
                    float ao  = CO1 * s2a[oc];
                    float ns1 = fmaf(R1, s1a[oc], a[u][oc]);
                    s1a[oc] = ns1;
                    s2a[oc] = fmaf(R1, s2a[oc], R1 * ns1);
                    float mv = fmaf(CRF, s2b[oc], ao);
                    unsigned b = (mv >= 20.f) ? 1u : 0u;
                    float spf = (float)b;
                    float nb1 = fmaf(R1, s1b[oc], spf);
                    s1b[oc] = nb1;
                    s2b[oc] = fmaf(R1, s2b[oc], R1 * nb1);
                    cm[oc] |= b << u;
                }
            }
            s1m[0][tid] = cm[0];
            s1m[1][tid] = cm[1];
            s1m[2][tid] = cm[2];
            s1m[3][tid] = cm[3];
        }
        __syncthreads();
        if (iw) {
            float a[TC][4];
#pragma unroll
            for (int u = 0; u < TC; ++u) { a[u][0]=0.f; a[u][1]=0.f; a[u][2]=0.f; a[u][3]=0.f; }
#pragma unroll 1
            for (int ic = 0; ic < 4; ++ic) {
                const unsigned* sp = &s1m[ic][ibase];
                const float4*   wp = (const float4*)&wL2[ic * 36];
#pragma unroll 1
                for (int dy = 0; dy < 3; ++dy) {
#pragma unroll
                    for (int dx = 0; dx < 3; ++dx) {
                        unsigned win = sp[dx];
                        float4 w = wp[dx];
#pragma unroll
                        for (int u = 0; u < TC; ++u) {
                            float f = (float)((win >> u) & 1u);
                            a[u][0] = fmaf(f, w.x, a[u][0]);
                            a[u][1] = fmaf(f, w.y, a[u][1]);
                            a[u][2] = fmaf(f, w.z, a[u][2]);
                            a[u][3] = fmaf(f, w.w, a[u][3]);
                        }
                    }
                    sp += R2S; wp += 3;
                }
            }
            unsigned cm[4] = {0, 0, 0, 0};
#pragma unroll
            for (int u = 0; u < TC; ++u) {
#pragma unroll
                for (int oc = 0; oc < 4; ++oc) {
                    float ao  = CO2 * s2c[oc];
                    float ns1 = fmaf(R2, s1c[oc], a[u][oc]);
                    s1c[oc] = ns1;
                    s2c[oc] = fmaf(R2, s2c[oc], R2 * ns1);
                    float mv = fmaf(CRF, s2d[oc], ao);
                    unsigned b = (mv >= 40.f) ? 1u : 0u;
                    float spf = (float)b;
                    float nd1 = fmaf(R2, s1d[oc], spf);
                    s1d[oc] = nd1;
                    s2d[oc] = fmaf(R2, s2d[oc], R2 * nd1);
                    cm[oc] |= b << u;
                }
            }
#pragma unroll
            for (int oc = 0; oc < 4; ++oc)
                om[oc] |= (unsigned long long)cm[oc] << t0;
        }
        __syncthreads();
    }
    if (iw) {
#pragma unroll
        for (int c = 0; c < 4; ++c) {
            float* p = out + ((size_t)(((n * 4 + c) * 128 + (Y0 + iy)) * 128 + (X0 + ix))) * 50;
            unsigned long long m = om[c];
#pragma unroll
            for (int j = 0; j < 25; ++j) {
                int k = 2 * j;
                float2 v;
                v.x = (float)((unsigned)(m >> k) & 1u);
                v.y = (float)((unsigned)(m >> (k + 1)) & 1u);
                *(float2*)(p + k) = v;
            }
        }
    }
}

extern "C" void kernel_launch(void* const* d_in, const int* in_sizes, int n_in,
                              void* d_out, int out_size, void* d_ws, size_t ws_size,
                              hipStream_t stream) {
    (void)in_sizes; (void)n_in; (void)out_size;
    const float* x  = (const float*)d_in[0];
    const float* w1 = (const float*)d_in[1];
    const float* w2 = (const float*)d_in[2];
    float* o = (float*)d_out;

    if (ws_size >= 2u * 4194304u) {
        uint2* xmg = (uint2*)d_ws;            // 4 MB, [n][c][yx]
        uint2* s1g = xmg + 524288;            // 4 MB, [n][c][yx]
        hipLaunchKernelGGL(snn_pack, dim3(2048), dim3(256), 0, stream, x, xmg);
        hipLaunchKernelGGL(snn_l1, dim3(8, 16, 8), dim3(256), 0, stream, xmg, w1, s1g);
        hipLaunchKernelGGL(snn_l2, dim3(8, 16, 8), dim3(256), 0, stream, s1g, w2, o);
    } else {
        dim3 grid(128 / TW, 128 / TH, 8);
        hipLaunchKernelGGL(snn_fused_fb, grid, dim3(256), 0, stream, x, w1, w2, o);
    }
}